// Round 8
// baseline (6163.233 us; speedup 1.0000x reference)
//
#include <hip/hip_runtime.h>

// ---------------------------------------------------------------------------
// Bidirectional stacked GRU decoder. B=64, S=512, I=H=512, L=2. f32 I/O.
//
// Round-8: persistent fused kernel with contention-free sync.
//   Grid 128 WGs = layer(2) x dir(2) x col-slice(32), 256 thr, 1 WG/CU.
//   Per WG: Wih+Whh 16-col slices LDS-resident (bf16), h master in REGISTERS.
//   Per step: [l0: prefetch x] -> poll per-WG flags (32-lane parallel load)
//   -> ring reads (agent-relaxed 8B atomics, coherent at IC) -> 96 MFMA ->
//   gate epilogue -> wave-local hpub staging -> ring publish -> vmcnt(0) ->
//   LDS-counter arrival; 4th wave stores flags[group][step][wg]=1 (plain
//   relaxed agent store, no RMW). No per-step __syncthreads at all.
//   Layer-1 lags layer-0 by 1 step (512-step critical path).
// ---------------------------------------------------------------------------

#define B_ 64
#define S_ 512
#define H_ 512
#define G3_ 1536

typedef __attribute__((ext_vector_type(8))) __bf16 bf16x8;
typedef __attribute__((ext_vector_type(8))) short short8;
typedef __attribute__((ext_vector_type(2))) unsigned long long ull2;
typedef __attribute__((ext_vector_type(4))) float f32x4;
typedef unsigned long long ull;

__device__ __forceinline__ unsigned short f2b(float f) {
  union { float f; unsigned int i; } v; v.f = f;
  unsigned int x = v.i;
  return (unsigned short)((x + 0x7fffu + ((x >> 16) & 1u)) >> 16);
}
__device__ __forceinline__ bf16x8 load8(const unsigned short* p) {
  short8 s = *(const short8*)p;
  return __builtin_bit_cast(bf16x8, s);
}
__device__ __forceinline__ bf16x8 load8f(const float* p) {
  f32x4 a = *(const f32x4*)p, b = *(const f32x4*)(p + 4);
  short8 s;
  s[0] = (short)f2b(a[0]); s[1] = (short)f2b(a[1]);
  s[2] = (short)f2b(a[2]); s[3] = (short)f2b(a[3]);
  s[4] = (short)f2b(b[0]); s[5] = (short)f2b(b[1]);
  s[6] = (short)f2b(b[2]); s[7] = (short)f2b(b[3]);
  return __builtin_bit_cast(bf16x8, s);
}
__device__ __forceinline__ f32x4 mfma16(bf16x8 a, bf16x8 b, f32x4 c) {
  return __builtin_amdgcn_mfma_f32_16x16x32_bf16(a, b, c, 0, 0, 0);
}
__device__ __forceinline__ float sigmoidf_(float x) {
  float e = __expf(-fabsf(x));
  float s = e / (1.0f + e);
  return x >= 0.0f ? 1.0f - s : s;
}
__device__ __forceinline__ float tanhf_(float x) {
  float e = __expf(-2.0f * fabsf(x));
  float r = (1.0f - e) / (1.0f + e);
  return x >= 0.0f ? r : -r;
}
// agent-scope coherent 16B (2x8B) ring read -> bf16x8
__device__ __forceinline__ bf16x8 load16a(ull* p) {
  ull2 v;
  v[0] = __hip_atomic_load(p, __ATOMIC_RELAXED, __HIP_MEMORY_SCOPE_AGENT);
  v[1] = __hip_atomic_load(p + 1, __ATOMIC_RELAXED, __HIP_MEMORY_SCOPE_AGENT);
  return __builtin_bit_cast(bf16x8, v);
}

// ---------------------------------------------------------------------------
// init ring slot 3 ("h before step 0") for all (layer,dir) from enc.
// ring layout (ull units): [(l*2+d)][slot(4)][8192]  (slot = [b(64)][512] bf16)
// ---------------------------------------------------------------------------
__global__ void init_ring(const float* __restrict__ enc, ull* __restrict__ ring) {
  int i = blockIdx.x * 256 + threadIdx.x;      // 0..32767
  if (i >= 32768) return;
  int ld = i >> 13;                            // (l*2+d)
  int d = ld & 1;
  int u = i & 8191;                            // ull index within slot
  int e4 = u * 4;
  int b = e4 >> 9, c = e4 & 511;
  const float* e = enc + b * 1024 + d * 512 + c;
  ull v = 0;
#pragma unroll
  for (int j = 0; j < 4; ++j) v |= (ull)f2b(e[j]) << (16 * j);
  ring[(size_t)ld * 32768 + 3 * 8192 + u] = v;
}

// ---------------------------------------------------------------------------
// Persistent fused GRU. Grid 128 = l(2) x d(2) x cb(32), block 256.
// flags layout: [(l*2+d)][step(512)][wg(32)] int
// ---------------------------------------------------------------------------
__global__ __launch_bounds__(256) void gru_fused(
    const float* __restrict__ x,               // [B][S][H] f32
    const float* __restrict__ enc,             // [B][2H] f32
    const float* __restrict__ WihF, const float* __restrict__ WihB,
    const float* __restrict__ WhhF, const float* __restrict__ WhhB,
    const float* __restrict__ bihF, const float* __restrict__ bihB,
    const float* __restrict__ bhhF, const float* __restrict__ bhhB,
    ull* __restrict__ ring,
    int* __restrict__ flags,
    float* __restrict__ dout) {                // [B][S][2H] f32
  __shared__ __align__(16) unsigned short wih[48 * 520];
  __shared__ __align__(16) unsigned short whh[48 * 520];
  __shared__ float hpub[64 * 17];              // wave-local publish staging
  __shared__ int lcnt[8];

  const int tid = threadIdx.x;
  const int lane = tid & 63;
  const int wv = tid >> 6;                     // 0..3
  const int wg = (int)blockIdx.x;
  const int l = wg >> 6, d = (wg >> 5) & 1, cb = wg & 31;
  const int colbase = cb * 16;
  const int rowA = lane & 15, kb = lane >> 4;

  const float* Wih = (d ? WihB : WihF) + (size_t)l * G3_ * H_;
  const float* Whh = (d ? WhhB : WhhF) + (size_t)l * G3_ * H_;
  const float* bi = (d ? bihB : bihF) + l * G3_;
  const float* bh = (d ? bhhB : bhhF) + l * G3_;

  if (tid < 8) lcnt[tid] = 0;
  // one-time LDS fill: 16-col slices of Wih/Whh (rows g*512+colbase+c), bf16
  for (int i = tid; i < 48 * 64; i += 256) {
    int r = i >> 6, j8 = (i & 63) * 8;         // r = g*16+c
    int g = r >> 4, c = r & 15;
    size_t gro = (size_t)(g * 512 + colbase + c) * H_ + j8;
    *(short8*)&wih[r * 520 + j8] = __builtin_bit_cast(short8, load8f(Wih + gro));
    *(short8*)&whh[r * 520 + j8] = __builtin_bit_cast(short8, load8f(Whh + gro));
  }
  __syncthreads();                             // prologue only

  const int col16 = rowA;
  const int hc = colbase + col16;
  const float brz_r = bi[hc] + bh[hc];
  const float brz_z = bi[512 + hc] + bh[512 + hc];
  const float bi_n = bi[1024 + hc];
  const float bh_n = bh[1024 + hc];

  const int bq = wv * 16 + kb * 4;             // C rows (batches) this lane owns
  const int arow = wv * 16 + rowA;             // A row this lane loads

  // h master in registers (each element read/written by exactly one thread)
  float hm[4];
#pragma unroll
  for (int rg = 0; rg < 4; ++rg)
    hm[rg] = enc[(size_t)(bq + rg) * 1024 + d * 512 + hc];

  int* fl0 = flags + d * (512 * 32);           // layer-0 group, this dir
  int* fl1 = flags + (2 + d) * (512 * 32);     // layer-1 group, this dir
  int* flo = flags + (l * 2 + d) * (512 * 32);
  ull* ring0 = ring + (size_t)d * 32768;
  ull* ringl = ring + (size_t)(l * 2 + d) * 32768;

  for (int t = 0; t < 512; ++t) {
    // x A-frags (layer 0): flag-independent — issue before the poll
    bf16x8 aIn[16];
    if (l == 0) {
      int txx = d ? (511 - t) : t;
      const float* ap = x + ((size_t)arow * 512 + txx) * 512 + kb * 8;
#pragma unroll
      for (int kk = 0; kk < 16; ++kk) aIn[kk] = load8f(ap + kk * 32);
    }

    // flag wait: lane<32 watches fl0[needA][lane], lane>=32 fl1[needB][lane-32]
    {
      const int needA = (l == 0) ? (t - 1) : t;        // producer row in fl0
      const int needB = (l == 0) ? (t - 4) : (t - 1);  // row in fl1
      int* watch = nullptr;
      if (lane < 32) { if (needA >= 0) watch = fl0 + needA * 32 + lane; }
      else           { if (needB >= 0) watch = fl1 + needB * 32 + (lane - 32); }
      if (watch) {
        while (__hip_atomic_load(watch, __ATOMIC_RELAXED,
                                 __HIP_MEMORY_SCOPE_AGENT) == 0)
          __builtin_amdgcn_s_sleep(1);
      }
    }

    if (l == 1) {                              // layer-0 output at step t
      ull* rp = ring0 + (size_t)(t & 3) * 8192;
#pragma unroll
      for (int kk = 0; kk < 16; ++kk) {
        int eb = arow * 512 + kk * 32 + kb * 8;
        aIn[kk] = load16a(rp + (eb >> 2));
      }
    }
    ull* rpo = ringl + (size_t)((t + 3) & 3) * 8192;   // own h_{t-1}
    bf16x8 aOwn[16];
#pragma unroll
    for (int kk = 0; kk < 16; ++kk) {
      int eb = arow * 512 + kk * 32 + kb * 8;
      aOwn[kk] = load16a(rpo + (eb >> 2));
    }

    f32x4 accr = {0,0,0,0}, accz = {0,0,0,0}, acni = {0,0,0,0}, acnh = {0,0,0,0};
#pragma unroll
    for (int kk = 0; kk < 16; ++kk) {
      const int o = kk * 32 + kb * 8;
      accr = mfma16(aIn[kk],  load8(&wih[col16 * 520 + o]), accr);
      accr = mfma16(aOwn[kk], load8(&whh[col16 * 520 + o]), accr);
      accz = mfma16(aIn[kk],  load8(&wih[(16 + col16) * 520 + o]), accz);
      accz = mfma16(aOwn[kk], load8(&whh[(16 + col16) * 520 + o]), accz);
      acni = mfma16(aIn[kk],  load8(&wih[(32 + col16) * 520 + o]), acni);
      acnh = mfma16(aOwn[kk], load8(&whh[(32 + col16) * 520 + o]), acnh);
    }

    const int tox = d ? (511 - t) : t;
#pragma unroll
    for (int rg = 0; rg < 4; ++rg) {
      int b = bq + rg;
      float r = sigmoidf_(accr[rg] + brz_r);
      float z = sigmoidf_(accz[rg] + brz_z);
      float n = tanhf_(acni[rg] + bi_n + r * (acnh[rg] + bh_n));
      float hnew = (1.0f - z) * n + z * hm[rg];
      hm[rg] = hnew;
      hpub[b * 17 + col16] = hnew;             // wave-local staging
      if (l == 1)
        dout[((size_t)b * 512 + tox) * 1024 + d * 512 + hc] = hnew;
    }
    asm volatile("" ::: "memory");             // keep hpub stores before reads

    // publish own 16-col slice (rows of OWN wave) to ring slot t&3
    {
      int b = tid >> 2, q = tid & 3;           // b in wv*16..wv*16+15
      ull v = 0;
#pragma unroll
      for (int j = 0; j < 4; ++j)
        v |= (ull)f2b(hpub[b * 17 + q * 4 + j]) << (16 * j);
      __hip_atomic_store(ringl + (size_t)(t & 3) * 8192 +
                             ((b * 512 + colbase + q * 4) >> 2),
                         v, __ATOMIC_RELAXED, __HIP_MEMORY_SCOPE_AGENT);
    }
    asm volatile("s_waitcnt vmcnt(0)" ::: "memory");   // ring stores at IC

    // intra-WG arrival; 4th wave sets this WG's per-step flag (no RMW on L3)
    if (lane == 0) {
      int old = atomicAdd(&lcnt[t & 7], 1);
      if (old == 3) {
        lcnt[t & 7] = 0;
        __hip_atomic_store(flo + t * 32 + cb, 1, __ATOMIC_RELAXED,
                           __HIP_MEMORY_SCOPE_AGENT);
      }
    }
  }
}

// ---------------------------------------------------------------------------
// Final hidden epilogue: h_f = out[:, S-1, :H], h_b = out[:, 0, H:2H]
// ---------------------------------------------------------------------------
__global__ void h_epi(float* __restrict__ dout) {
  int i = blockIdx.x * 256 + threadIdx.x;      // 0 .. 65535
  if (i >= B_ * 2 * H_) return;
  int b = i >> 10, j = i & 1023;
  int t = (j < H_) ? (S_ - 1) : 0;
  dout[(size_t)B_ * S_ * 2 * H_ + i] = dout[((size_t)b * S_ + t) * (2 * H_) + j];
}

// ---------------------------------------------------------------------------
extern "C" void kernel_launch(void* const* d_in, const int* in_sizes, int n_in,
                              void* d_out, int out_size, void* d_ws, size_t ws_size,
                              hipStream_t stream) {
  const float* x    = (const float*)d_in[0];
  const float* enc  = (const float*)d_in[1];
  const float* WihF = (const float*)d_in[2];
  const float* WhhF = (const float*)d_in[3];
  const float* bihF = (const float*)d_in[4];
  const float* bhhF = (const float*)d_in[5];
  const float* WihB = (const float*)d_in[6];
  const float* WhhB = (const float*)d_in[7];
  const float* bihB = (const float*)d_in[8];
  const float* bhhB = (const float*)d_in[9];
  float* out = (float*)d_out;

  // ws: [flags 256KB][ring 1MB]
  char* ws = (char*)d_ws;
  int* flags = (int*)ws;                       // 4*512*32*4 = 262144 B
  ull* ring  = (ull*)(ws + 262144);

  (void)hipMemsetAsync(flags, 0, 262144, stream);
  init_ring<<<128, 256, 0, stream>>>(enc, ring);
  gru_fused<<<128, 256, 0, stream>>>(x, enc, WihF, WihB, WhhF, WhhB,
                                     bihF, bihB, bhhF, bhhB,
                                     ring, flags, out);
  h_epi<<<256, 256, 0, stream>>>(out);
}

// Round 9
// 3790.057 us; speedup vs baseline: 1.6262x; 1.6262x over previous
//
#include <hip/hip_runtime.h>

// ---------------------------------------------------------------------------
// Bidirectional stacked GRU decoder. B=64, S=512, I=H=512, L=2. f32 I/O.
//
// Round-9: R8 persistent structure + layout surgery.
//  - ring slots re-laid out [cell(64)][b(64)][8 bf16] -> every ring gather /
//    publish instruction is contiguous 256B segments (was 64x8B scatter).
//  - x pre-converted to bf16 in ws as xc[t][cell][b][8] (same coalesced
//    pattern; removes per-step f32->bf16 VALU; gated on ws_size).
//  - weight LDS layout [gate][kk][lane][8] -> ds_read_b128 at base+lane*16,
//    zero bank conflicts (was 8-way at 1040B row stride).
//  - hpub row stride 20 f32 (16B-aligned f32x4 publish reads).
// Sync unchanged from R8: per-WG flags, 32-lane parallel poll, no per-step
// __syncthreads, vmcnt(0) drain before flag store. Layer-1 lags by 1 step.
// ---------------------------------------------------------------------------

#define B_ 64
#define S_ 512
#define H_ 512
#define G3_ 1536

typedef __attribute__((ext_vector_type(8))) __bf16 bf16x8;
typedef __attribute__((ext_vector_type(8))) short short8;
typedef __attribute__((ext_vector_type(2))) unsigned long long ull2;
typedef __attribute__((ext_vector_type(4))) float f32x4;
typedef unsigned long long ull;

__device__ __forceinline__ unsigned short f2b(float f) {
  union { float f; unsigned int i; } v; v.f = f;
  unsigned int x = v.i;
  return (unsigned short)((x + 0x7fffu + ((x >> 16) & 1u)) >> 16);
}
__device__ __forceinline__ bf16x8 load8(const unsigned short* p) {
  short8 s = *(const short8*)p;
  return __builtin_bit_cast(bf16x8, s);
}
__device__ __forceinline__ bf16x8 load8f(const float* p) {
  f32x4 a = *(const f32x4*)p, b = *(const f32x4*)(p + 4);
  short8 s;
  s[0] = (short)f2b(a[0]); s[1] = (short)f2b(a[1]);
  s[2] = (short)f2b(a[2]); s[3] = (short)f2b(a[3]);
  s[4] = (short)f2b(b[0]); s[5] = (short)f2b(b[1]);
  s[6] = (short)f2b(b[2]); s[7] = (short)f2b(b[3]);
  return __builtin_bit_cast(bf16x8, s);
}
__device__ __forceinline__ f32x4 mfma16(bf16x8 a, bf16x8 b, f32x4 c) {
  return __builtin_amdgcn_mfma_f32_16x16x32_bf16(a, b, c, 0, 0, 0);
}
__device__ __forceinline__ float sigmoidf_(float x) {
  float e = __expf(-fabsf(x));
  float s = e / (1.0f + e);
  return x >= 0.0f ? 1.0f - s : s;
}
__device__ __forceinline__ float tanhf_(float x) {
  float e = __expf(-2.0f * fabsf(x));
  float r = (1.0f - e) / (1.0f + e);
  return x >= 0.0f ? r : -r;
}
// agent-scope coherent 16B (2x8B) ring read -> bf16x8
__device__ __forceinline__ bf16x8 load16a(ull* p) {
  ull2 v;
  v[0] = __hip_atomic_load(p, __ATOMIC_RELAXED, __HIP_MEMORY_SCOPE_AGENT);
  v[1] = __hip_atomic_load(p + 1, __ATOMIC_RELAXED, __HIP_MEMORY_SCOPE_AGENT);
  return __builtin_bit_cast(bf16x8, v);
}
// plain cached 16B load (xc: produced by a prior kernel, safe to cache)
__device__ __forceinline__ bf16x8 load16p(const ull* p) {
  ull2 v = *(const ull2*)p;
  return __builtin_bit_cast(bf16x8, v);
}
__device__ __forceinline__ ull pack4(const float* f) {
  ull v = 0;
#pragma unroll
  for (int j = 0; j < 4; ++j) v |= (ull)f2b(f[j]) << (16 * j);
  return v;
}

// ---------------------------------------------------------------------------
// xc[t][cell(64)][b(64)][8 bf16]  <-  x[b][t][cell*8+j]   (2,097,152 entries)
// ---------------------------------------------------------------------------
__global__ void cvt_x(const float* __restrict__ x, ull* __restrict__ xc) {
  int i = blockIdx.x * 256 + threadIdx.x;      // 0 .. 2^21-1
  int b = i & 63, cell = (i >> 6) & 63, txx = i >> 12;
  const float* src = x + ((size_t)b * 512 + txx) * 512 + cell * 8;
  float s0[4] = {src[0], src[1], src[2], src[3]};
  float s1[4] = {src[4], src[5], src[6], src[7]};
  size_t o = ((size_t)txx * 4096 + cell * 64 + b) * 2;
  xc[o]     = pack4(s0);
  xc[o + 1] = pack4(s1);
}

// ---------------------------------------------------------------------------
// init ring slot 3 ("h before step 0"): ring[(ld)][slot][cell][b][half]
// ---------------------------------------------------------------------------
__global__ void init_ring(const float* __restrict__ enc, ull* __restrict__ ring) {
  int i = blockIdx.x * 256 + threadIdx.x;      // 0..32767
  if (i >= 32768) return;
  int ld = i >> 13;                            // (l*2+d)
  int d = ld & 1;
  int rest = i & 8191;                         // (cell*64+b)*2+half
  int half = rest & 1, b = (rest >> 1) & 63, cell = rest >> 7;
  const float* e = enc + (size_t)b * 1024 + d * 512 + cell * 8 + half * 4;
  float s[4] = {e[0], e[1], e[2], e[3]};
  ring[(size_t)ld * 32768 + 3 * 8192 + rest] = pack4(s);
}

// ---------------------------------------------------------------------------
// Persistent fused GRU. Grid 128 = l(2) x d(2) x cb(32), block 256.
// flags layout: [(l*2+d)][step(512)][wg(32)] int
// ---------------------------------------------------------------------------
__global__ __launch_bounds__(256) void gru_fused(
    const float* __restrict__ x,               // [B][S][H] f32 (fallback path)
    const ull* __restrict__ xc, int usexc,     // coalesced bf16 x
    const float* __restrict__ enc,
    const float* __restrict__ WihF, const float* __restrict__ WihB,
    const float* __restrict__ WhhF, const float* __restrict__ WhhB,
    const float* __restrict__ bihF, const float* __restrict__ bihB,
    const float* __restrict__ bhhF, const float* __restrict__ bhhB,
    ull* __restrict__ ring,
    int* __restrict__ flags,
    float* __restrict__ dout) {                // [B][S][2H] f32
  __shared__ __align__(16) unsigned short wih2[24576];  // [gate][kk][lane][8]
  __shared__ __align__(16) unsigned short whh2[24576];
  __shared__ float hpub[64 * 20];              // [b][20] padded, wave-local
  __shared__ int lcnt[8];

  const int tid = threadIdx.x;
  const int lane = tid & 63;
  const int wv = tid >> 6;                     // 0..3
  const int wg = (int)blockIdx.x;
  const int l = wg >> 6, d = (wg >> 5) & 1, cb = wg & 31;
  const int colbase = cb * 16;
  const int rowA = lane & 15, kb = lane >> 4;

  const float* Wih = (d ? WihB : WihF) + (size_t)l * G3_ * H_;
  const float* Whh = (d ? WhhB : WhhF) + (size_t)l * G3_ * H_;
  const float* bi = (d ? bihB : bihF) + l * G3_;
  const float* bh = (d ? bhhB : bhhF) + l * G3_;

  if (tid < 8) lcnt[tid] = 0;
  // one-time LDS fill, layout [gate(3)][kk(16)][lane(64)][8]:
  // entry(gate,kk,lane=(k*16+c)) = W[gate*512+colbase+c][kk*32+k*8 .. +8]
  for (int i = tid; i < 3072; i += 256) {
    int gate = i >> 10;
    int rest = i & 1023;
    int kk = rest >> 6;
    int l6 = rest & 63;
    int c = l6 & 15, k = l6 >> 4;
    size_t gro = (size_t)(gate * 512 + colbase + c) * 512 + kk * 32 + k * 8;
    *(short8*)&wih2[i * 8] = __builtin_bit_cast(short8, load8f(Wih + gro));
    *(short8*)&whh2[i * 8] = __builtin_bit_cast(short8, load8f(Whh + gro));
  }
  __syncthreads();                             // prologue only

  const int col16 = rowA;
  const int hc = colbase + col16;
  const float brz_r = bi[hc] + bh[hc];
  const float brz_z = bi[512 + hc] + bh[512 + hc];
  const float bi_n = bi[1024 + hc];
  const float bh_n = bh[1024 + hc];

  const int bq = wv * 16 + kb * 4;             // C rows (batches) this lane owns
  const int arow = wv * 16 + rowA;             // A row this lane loads

  float hm[4];
#pragma unroll
  for (int rg = 0; rg < 4; ++rg)
    hm[rg] = enc[(size_t)(bq + rg) * 1024 + d * 512 + hc];

  int* fl0 = flags + d * (512 * 32);
  int* fl1 = flags + (2 + d) * (512 * 32);
  int* flo = flags + (l * 2 + d) * (512 * 32);
  ull* ring0 = ring + (size_t)d * 32768;
  ull* ringl = ring + (size_t)(l * 2 + d) * 32768;

  // publish mapping (wave-local): lane -> row wv*16+(lane>>2),
  // cellL=(lane>>1)&1, half=lane&1
  const int prow = wv * 16 + (lane >> 2);
  const int pcellL = (lane >> 1) & 1;
  const int phalf = lane & 1;
  const int pc0 = pcellL * 8 + phalf * 4;
  const int pidx = ((2 * cb + pcellL) * 64 + prow) * 2 + phalf;

  for (int t = 0; t < 512; ++t) {
    // x A-frags (layer 0): flag-independent — issue before the poll
    bf16x8 aIn[16];
    if (l == 0) {
      int txx = d ? (511 - t) : t;
      if (usexc) {
        const ull* xp = xc + (size_t)txx * 8192;
#pragma unroll
        for (int kk = 0; kk < 16; ++kk)
          aIn[kk] = load16p(xp + (size_t)((kk * 4 + kb) * 64 + arow) * 2);
      } else {
        const float* ap = x + ((size_t)arow * 512 + txx) * 512 + kb * 8;
#pragma unroll
        for (int kk = 0; kk < 16; ++kk) aIn[kk] = load8f(ap + kk * 32);
      }
    }

    // flag wait: lane<32 watches fl0[needA][lane], lane>=32 fl1[needB][lane-32]
    {
      const int needA = (l == 0) ? (t - 1) : t;
      const int needB = (l == 0) ? (t - 4) : (t - 1);
      int* watch = nullptr;
      if (lane < 32) { if (needA >= 0) watch = fl0 + needA * 32 + lane; }
      else           { if (needB >= 0) watch = fl1 + needB * 32 + (lane - 32); }
      if (watch) {
        while (__hip_atomic_load(watch, __ATOMIC_RELAXED,
                                 __HIP_MEMORY_SCOPE_AGENT) == 0)
          __builtin_amdgcn_s_sleep(1);
      }
    }

    if (l == 1) {                              // layer-0 output at step t
      ull* rp = ring0 + (size_t)(t & 3) * 8192;
#pragma unroll
      for (int kk = 0; kk < 16; ++kk)
        aIn[kk] = load16a(rp + (size_t)((kk * 4 + kb) * 64 + arow) * 2);
    }
    ull* rpo = ringl + (size_t)((t + 3) & 3) * 8192;   // own h_{t-1}
    bf16x8 aOwn[16];
#pragma unroll
    for (int kk = 0; kk < 16; ++kk)
      aOwn[kk] = load16a(rpo + (size_t)((kk * 4 + kb) * 64 + arow) * 2);

    f32x4 accr = {0,0,0,0}, accz = {0,0,0,0}, acni = {0,0,0,0}, acnh = {0,0,0,0};
#pragma unroll
    for (int kk = 0; kk < 16; ++kk) {
      const int o = kk * 512 + lane * 8;       // [kk][lane][8] within gate blk
      accr = mfma16(aIn[kk],  load8(&wih2[o]), accr);
      accr = mfma16(aOwn[kk], load8(&whh2[o]), accr);
      accz = mfma16(aIn[kk],  load8(&wih2[8192 + o]), accz);
      accz = mfma16(aOwn[kk], load8(&whh2[8192 + o]), accz);
      acni = mfma16(aIn[kk],  load8(&wih2[16384 + o]), acni);
      acnh = mfma16(aOwn[kk], load8(&whh2[16384 + o]), acnh);
    }

    const int tox = d ? (511 - t) : t;
#pragma unroll
    for (int rg = 0; rg < 4; ++rg) {
      int b = bq + rg;
      float r = sigmoidf_(accr[rg] + brz_r);
      float z = sigmoidf_(accz[rg] + brz_z);
      float n = tanhf_(acni[rg] + bi_n + r * (acnh[rg] + bh_n));
      float hnew = (1.0f - z) * n + z * hm[rg];
      hm[rg] = hnew;
      hpub[b * 20 + col16] = hnew;             // wave-local staging
      if (l == 1)
        dout[((size_t)b * 512 + tox) * 1024 + d * 512 + hc] = hnew;
    }
    asm volatile("" ::: "memory");

    // publish own 16-col slice (wave-local rows) to ring slot t&3, coalesced
    {
      f32x4 v4 = *(f32x4*)&hpub[prow * 20 + pc0];
      float s[4] = {v4[0], v4[1], v4[2], v4[3]};
      __hip_atomic_store(ringl + (size_t)(t & 3) * 8192 + pidx, pack4(s),
                         __ATOMIC_RELAXED, __HIP_MEMORY_SCOPE_AGENT);
    }
    asm volatile("s_waitcnt vmcnt(0)" ::: "memory");   // ring stores at IC

    // intra-WG arrival; 4th wave sets this WG's per-step flag (no global RMW)
    if (lane == 0) {
      int old = atomicAdd(&lcnt[t & 7], 1);
      if (old == 3) {
        lcnt[t & 7] = 0;
        __hip_atomic_store(flo + t * 32 + cb, 1, __ATOMIC_RELAXED,
                           __HIP_MEMORY_SCOPE_AGENT);
      }
    }
  }
}

// ---------------------------------------------------------------------------
// Final hidden epilogue: h_f = out[:, S-1, :H], h_b = out[:, 0, H:2H]
// ---------------------------------------------------------------------------
__global__ void h_epi(float* __restrict__ dout) {
  int i = blockIdx.x * 256 + threadIdx.x;      // 0 .. 65535
  if (i >= B_ * 2 * H_) return;
  int b = i >> 10, j = i & 1023;
  int t = (j < H_) ? (S_ - 1) : 0;
  dout[(size_t)B_ * S_ * 2 * H_ + i] = dout[((size_t)b * S_ + t) * (2 * H_) + j];
}

// ---------------------------------------------------------------------------
extern "C" void kernel_launch(void* const* d_in, const int* in_sizes, int n_in,
                              void* d_out, int out_size, void* d_ws, size_t ws_size,
                              hipStream_t stream) {
  const float* x    = (const float*)d_in[0];
  const float* enc  = (const float*)d_in[1];
  const float* WihF = (const float*)d_in[2];
  const float* WhhF = (const float*)d_in[3];
  const float* bihF = (const float*)d_in[4];
  const float* bhhF = (const float*)d_in[5];
  const float* WihB = (const float*)d_in[6];
  const float* WhhB = (const float*)d_in[7];
  const float* bihB = (const float*)d_in[8];
  const float* bhhB = (const float*)d_in[9];
  float* out = (float*)d_out;

  // ws: [flags 256KB][ring 1MB][xc 32MB (optional)]
  char* ws = (char*)d_ws;
  int* flags = (int*)ws;                       // 4*512*32*4 = 262,144 B
  ull* ring  = (ull*)(ws + 262144);            // 4*4*64KB = 1,048,576 B
  ull* xc    = (ull*)(ws + 262144 + 1048576);  // 33,554,432 B
  const int usexc = (ws_size >= (size_t)262144 + 1048576 + 33554432) ? 1 : 0;

  (void)hipMemsetAsync(flags, 0, 262144, stream);
  if (usexc) cvt_x<<<8192, 256, 0, stream>>>(x, xc);
  init_ring<<<128, 256, 0, stream>>>(enc, ring);
  gru_fused<<<128, 256, 0, stream>>>(x, xc, usexc, enc,
                                     WihF, WihB, WhhF, WhhB,
                                     bihF, bihB, bhhF, bhhB,
                                     ring, flags, out);
  h_epi<<<256, 256, 0, stream>>>(out);
}

// Round 10
// 2777.929 us; speedup vs baseline: 2.2186x; 1.3643x over previous
//
#include <hip/hip_runtime.h>

// ---------------------------------------------------------------------------
// Bidirectional stacked GRU decoder. B=64, S=512, I=H=512, L=2. f32 I/O.
//
// Round-10 = R9 + sync-path decongestion:
//  - per-WG PRIVATE 128B flag lines with monotonically increasing generation
//    values (flag[g][wg] = t+1 after step t). No shared flag cache lines ->
//    no IC line serialization among 32 producers; consumers poll 32 distinct
//    lines with one 32-lane parallel load.
//  - dout stores moved AFTER the flag publish (off the per-step critical
//    chain); vmcnt(0) drain covers only the 8B ring publish store.
//  - ring depth 8 (slack between the two layer pipelines).
//  - busy poll (no s_sleep).
// Dataflow unchanged from R9: 128 persistent WGs = l(2) x d(2) x cb(32);
// weights LDS-resident bf16 [gate][kk][lane][8]; h master in registers;
// h exchanged via coalesced bf16 ring [cell][b][8] with agent-relaxed 8B
// atomics; xc = pre-converted bf16 x (coalesced), gated on ws_size.
// ---------------------------------------------------------------------------

#define B_ 64
#define S_ 512
#define H_ 512
#define G3_ 1536

typedef __attribute__((ext_vector_type(8))) __bf16 bf16x8;
typedef __attribute__((ext_vector_type(8))) short short8;
typedef __attribute__((ext_vector_type(2))) unsigned long long ull2;
typedef __attribute__((ext_vector_type(4))) float f32x4;
typedef unsigned long long ull;

__device__ __forceinline__ unsigned short f2b(float f) {
  union { float f; unsigned int i; } v; v.f = f;
  unsigned int x = v.i;
  return (unsigned short)((x + 0x7fffu + ((x >> 16) & 1u)) >> 16);
}
__device__ __forceinline__ bf16x8 load8(const unsigned short* p) {
  short8 s = *(const short8*)p;
  return __builtin_bit_cast(bf16x8, s);
}
__device__ __forceinline__ bf16x8 load8f(const float* p) {
  f32x4 a = *(const f32x4*)p, b = *(const f32x4*)(p + 4);
  short8 s;
  s[0] = (short)f2b(a[0]); s[1] = (short)f2b(a[1]);
  s[2] = (short)f2b(a[2]); s[3] = (short)f2b(a[3]);
  s[4] = (short)f2b(b[0]); s[5] = (short)f2b(b[1]);
  s[6] = (short)f2b(b[2]); s[7] = (short)f2b(b[3]);
  return __builtin_bit_cast(bf16x8, s);
}
__device__ __forceinline__ f32x4 mfma16(bf16x8 a, bf16x8 b, f32x4 c) {
  return __builtin_amdgcn_mfma_f32_16x16x32_bf16(a, b, c, 0, 0, 0);
}
__device__ __forceinline__ float sigmoidf_(float x) {
  float e = __expf(-fabsf(x));
  float s = e / (1.0f + e);
  return x >= 0.0f ? 1.0f - s : s;
}
__device__ __forceinline__ float tanhf_(float x) {
  float e = __expf(-2.0f * fabsf(x));
  float r = (1.0f - e) / (1.0f + e);
  return x >= 0.0f ? r : -r;
}
// agent-scope coherent 16B (2x8B) ring read -> bf16x8
__device__ __forceinline__ bf16x8 load16a(ull* p) {
  ull2 v;
  v[0] = __hip_atomic_load(p, __ATOMIC_RELAXED, __HIP_MEMORY_SCOPE_AGENT);
  v[1] = __hip_atomic_load(p + 1, __ATOMIC_RELAXED, __HIP_MEMORY_SCOPE_AGENT);
  return __builtin_bit_cast(bf16x8, v);
}
__device__ __forceinline__ bf16x8 load16p(const ull* p) {
  ull2 v = *(const ull2*)p;
  return __builtin_bit_cast(bf16x8, v);
}
__device__ __forceinline__ ull pack4(const float* f) {
  ull v = 0;
#pragma unroll
  for (int j = 0; j < 4; ++j) v |= (ull)f2b(f[j]) << (16 * j);
  return v;
}

// ---------------------------------------------------------------------------
// xc[t][cell(64)][b(64)][8 bf16]  <-  x[b][t][cell*8+j]
// ---------------------------------------------------------------------------
__global__ void cvt_x(const float* __restrict__ x, ull* __restrict__ xc) {
  int i = blockIdx.x * 256 + threadIdx.x;      // 0 .. 2^21-1
  int b = i & 63, cell = (i >> 6) & 63, txx = i >> 12;
  const float* src = x + ((size_t)b * 512 + txx) * 512 + cell * 8;
  float s0[4] = {src[0], src[1], src[2], src[3]};
  float s1[4] = {src[4], src[5], src[6], src[7]};
  size_t o = ((size_t)txx * 4096 + cell * 64 + b) * 2;
  xc[o]     = pack4(s0);
  xc[o + 1] = pack4(s1);
}

// ---------------------------------------------------------------------------
// init ring slot 7 ("h before step 0"): ring[(ld)][slot(8)][cell][b][half]
// ---------------------------------------------------------------------------
__global__ void init_ring(const float* __restrict__ enc, ull* __restrict__ ring) {
  int i = blockIdx.x * 256 + threadIdx.x;      // 0..32767
  if (i >= 32768) return;
  int ld = i >> 13;                            // (l*2+d)
  int d = ld & 1;
  int rest = i & 8191;                         // (cell*64+b)*2+half
  int half = rest & 1, b = (rest >> 1) & 63, cell = rest >> 7;
  const float* e = enc + (size_t)b * 1024 + d * 512 + cell * 8 + half * 4;
  float s[4] = {e[0], e[1], e[2], e[3]};
  ring[(size_t)ld * 65536 + 7 * 8192 + rest] = pack4(s);
}

// ---------------------------------------------------------------------------
// Persistent fused GRU. Grid 128 = l(2) x d(2) x cb(32), block 256.
// flags: [(l*2+d)][wg(32)] x 32 ints (one 128B line per WG), value = t+1.
// ---------------------------------------------------------------------------
__global__ __launch_bounds__(256) void gru_fused(
    const float* __restrict__ x,               // [B][S][H] f32 (fallback path)
    const ull* __restrict__ xc, int usexc,     // coalesced bf16 x
    const float* __restrict__ enc,
    const float* __restrict__ WihF, const float* __restrict__ WihB,
    const float* __restrict__ WhhF, const float* __restrict__ WhhB,
    const float* __restrict__ bihF, const float* __restrict__ bihB,
    const float* __restrict__ bhhF, const float* __restrict__ bhhB,
    ull* __restrict__ ring,
    unsigned int* __restrict__ flags,
    float* __restrict__ dout) {                // [B][S][2H] f32
  __shared__ __align__(16) unsigned short wih2[24576];  // [gate][kk][lane][8]
  __shared__ __align__(16) unsigned short whh2[24576];
  __shared__ float hpub[64 * 20];              // [b][20] padded, wave-local
  __shared__ int lcnt[8];

  const int tid = threadIdx.x;
  const int lane = tid & 63;
  const int wv = tid >> 6;                     // 0..3
  const int wg = (int)blockIdx.x;
  const int l = wg >> 6, d = (wg >> 5) & 1, cb = wg & 31;
  const int colbase = cb * 16;
  const int rowA = lane & 15, kb = lane >> 4;

  const float* Wih = (d ? WihB : WihF) + (size_t)l * G3_ * H_;
  const float* Whh = (d ? WhhB : WhhF) + (size_t)l * G3_ * H_;
  const float* bi = (d ? bihB : bihF) + l * G3_;
  const float* bh = (d ? bhhB : bhhF) + l * G3_;

  if (tid < 8) lcnt[tid] = 0;
  // one-time LDS fill, layout [gate(3)][kk(16)][lane(64)][8]:
  for (int i = tid; i < 3072; i += 256) {
    int gate = i >> 10;
    int rest = i & 1023;
    int kk = rest >> 6;
    int l6 = rest & 63;
    int c = l6 & 15, k = l6 >> 4;
    size_t gro = (size_t)(gate * 512 + colbase + c) * 512 + kk * 32 + k * 8;
    *(short8*)&wih2[i * 8] = __builtin_bit_cast(short8, load8f(Wih + gro));
    *(short8*)&whh2[i * 8] = __builtin_bit_cast(short8, load8f(Whh + gro));
  }
  __syncthreads();                             // prologue only

  const int col16 = rowA;
  const int hc = colbase + col16;
  const float brz_r = bi[hc] + bh[hc];
  const float brz_z = bi[512 + hc] + bh[512 + hc];
  const float bi_n = bi[1024 + hc];
  const float bh_n = bh[1024 + hc];

  const int bq = wv * 16 + kb * 4;             // C rows (batches) this lane owns
  const int arow = wv * 16 + rowA;             // A row this lane loads

  float hm[4];
#pragma unroll
  for (int rg = 0; rg < 4; ++rg)
    hm[rg] = enc[(size_t)(bq + rg) * 1024 + d * 512 + hc];

  // flag bases (32 ints = 128B per WG line)
  unsigned int* fl0 = flags + d * (32 * 32);
  unsigned int* fl1 = flags + (2 + d) * (32 * 32);
  unsigned int* flo = flags + (l * 2 + d) * (32 * 32);
  ull* ring0 = ring + (size_t)d * 65536;
  ull* ringl = ring + (size_t)(l * 2 + d) * 65536;

  // publish mapping (wave-local rows)
  const int prow = wv * 16 + (lane >> 2);
  const int pcellL = (lane >> 1) & 1;
  const int phalf = lane & 1;
  const int pc0 = pcellL * 8 + phalf * 4;
  const int pidx = ((2 * cb + pcellL) * 64 + prow) * 2 + phalf;

  for (int t = 0; t < 512; ++t) {
    // x A-frags (layer 0): flag-independent — issue before the poll
    bf16x8 aIn[16];
    if (l == 0) {
      int txx = d ? (511 - t) : t;
      if (usexc) {
        const ull* xp = xc + (size_t)txx * 8192;
#pragma unroll
        for (int kk = 0; kk < 16; ++kk)
          aIn[kk] = load16p(xp + (size_t)((kk * 4 + kb) * 64 + arow) * 2);
      } else {
        const float* ap = x + ((size_t)arow * 512 + txx) * 512 + kb * 8;
#pragma unroll
        for (int kk = 0; kk < 16; ++kk) aIn[kk] = load8f(ap + kk * 32);
      }
    }

    // generation poll: lane<32 watches fl0[lane], lane>=32 watches fl1[lane-32]
    // l0 step t: fl0 >= t (own prev), fl1 >= t-7 (slot reuse guard)
    // l1 step t: fl0 >= t+1 (producer), fl1 >= t (own prev)
    {
      const int needA = (l == 0) ? t : (t + 1);
      const int needB = (l == 0) ? (t - 7) : t;
      unsigned int* watch;
      int need;
      if (lane < 32) { watch = fl0 + lane * 32;        need = needA; }
      else           { watch = fl1 + (lane - 32) * 32; need = needB; }
      if (need > 0) {
        while (__hip_atomic_load(watch, __ATOMIC_RELAXED,
                                 __HIP_MEMORY_SCOPE_AGENT) < (unsigned)need) {}
      }
    }
    asm volatile("" ::: "memory");             // no hoisting of ring reads

    if (l == 1) {                              // layer-0 output at step t
      ull* rp = ring0 + (size_t)(t & 7) * 8192;
#pragma unroll
      for (int kk = 0; kk < 16; ++kk)
        aIn[kk] = load16a(rp + (size_t)((kk * 4 + kb) * 64 + arow) * 2);
    }
    ull* rpo = ringl + (size_t)((t + 7) & 7) * 8192;   // own h_{t-1}
    bf16x8 aOwn[16];
#pragma unroll
    for (int kk = 0; kk < 16; ++kk)
      aOwn[kk] = load16a(rpo + (size_t)((kk * 4 + kb) * 64 + arow) * 2);

    f32x4 accr = {0,0,0,0}, accz = {0,0,0,0}, acni = {0,0,0,0}, acnh = {0,0,0,0};
#pragma unroll
    for (int kk = 0; kk < 16; ++kk) {
      const int o = kk * 512 + lane * 8;       // [kk][lane][8] within gate blk
      accr = mfma16(aIn[kk],  load8(&wih2[o]), accr);
      accr = mfma16(aOwn[kk], load8(&whh2[o]), accr);
      accz = mfma16(aIn[kk],  load8(&wih2[8192 + o]), accz);
      accz = mfma16(aOwn[kk], load8(&whh2[8192 + o]), accz);
      acni = mfma16(aIn[kk],  load8(&wih2[16384 + o]), acni);
      acnh = mfma16(aOwn[kk], load8(&whh2[16384 + o]), acnh);
    }

#pragma unroll
    for (int rg = 0; rg < 4; ++rg) {
      float r = sigmoidf_(accr[rg] + brz_r);
      float z = sigmoidf_(accz[rg] + brz_z);
      float n = tanhf_(acni[rg] + bi_n + r * (acnh[rg] + bh_n));
      float hnew = (1.0f - z) * n + z * hm[rg];
      hm[rg] = hnew;
      hpub[(bq + rg) * 20 + col16] = hnew;     // wave-local staging
    }
    asm volatile("" ::: "memory");

    // publish own 16-col slice (wave-local rows) to ring slot t&7, coalesced
    {
      f32x4 v4 = *(f32x4*)&hpub[prow * 20 + pc0];
      float s[4] = {v4[0], v4[1], v4[2], v4[3]};
      __hip_atomic_store(ringl + (size_t)(t & 7) * 8192 + pidx, pack4(s),
                         __ATOMIC_RELAXED, __HIP_MEMORY_SCOPE_AGENT);
    }
    asm volatile("s_waitcnt vmcnt(0)" ::: "memory");   // ring store at IC

    // intra-WG arrival; 4th wave bumps this WG's generation flag (own line)
    if (lane == 0) {
      int old = atomicAdd(&lcnt[t & 7], 1);
      if (old == 3) {
        lcnt[t & 7] = 0;
        __hip_atomic_store(flo + cb * 32, (unsigned)(t + 1),
                           __ATOMIC_RELAXED, __HIP_MEMORY_SCOPE_AGENT);
      }
    }

    // dout stores AFTER the flag publish — off the critical chain
    if (l == 1) {
      const int tox = d ? (511 - t) : t;
#pragma unroll
      for (int rg = 0; rg < 4; ++rg)
        dout[((size_t)(bq + rg) * 512 + tox) * 1024 + d * 512 + hc] = hm[rg];
    }
  }
}

// ---------------------------------------------------------------------------
// Final hidden epilogue: h_f = out[:, S-1, :H], h_b = out[:, 0, H:2H]
// ---------------------------------------------------------------------------
__global__ void h_epi(float* __restrict__ dout) {
  int i = blockIdx.x * 256 + threadIdx.x;      // 0 .. 65535
  if (i >= B_ * 2 * H_) return;
  int b = i >> 10, j = i & 1023;
  int t = (j < H_) ? (S_ - 1) : 0;
  dout[(size_t)B_ * S_ * 2 * H_ + i] = dout[((size_t)b * S_ + t) * (2 * H_) + j];
}

// ---------------------------------------------------------------------------
extern "C" void kernel_launch(void* const* d_in, const int* in_sizes, int n_in,
                              void* d_out, int out_size, void* d_ws, size_t ws_size,
                              hipStream_t stream) {
  const float* x    = (const float*)d_in[0];
  const float* enc  = (const float*)d_in[1];
  const float* WihF = (const float*)d_in[2];
  const float* WhhF = (const float*)d_in[3];
  const float* bihF = (const float*)d_in[4];
  const float* bhhF = (const float*)d_in[5];
  const float* WihB = (const float*)d_in[6];
  const float* WhhB = (const float*)d_in[7];
  const float* bihB = (const float*)d_in[8];
  const float* bhhB = (const float*)d_in[9];
  float* out = (float*)d_out;

  // ws: [flags 16KB (+pad to 64KB)][ring 2MB][xc 32MB (optional)]
  char* ws = (char*)d_ws;
  unsigned int* flags = (unsigned int*)ws;     // 4*32*128B = 16,384 B
  ull* ring  = (ull*)(ws + 65536);             // 4*8*64KB = 2,097,152 B
  ull* xc    = (ull*)(ws + 65536 + 2097152);   // 33,554,432 B
  const int usexc = (ws_size >= (size_t)65536 + 2097152 + 33554432) ? 1 : 0;

  (void)hipMemsetAsync(flags, 0, 16384, stream);
  if (usexc) cvt_x<<<8192, 256, 0, stream>>>(x, xc);
  init_ring<<<128, 256, 0, stream>>>(enc, ring);
  gru_fused<<<128, 256, 0, stream>>>(x, xc, usexc, enc,
                                     WihF, WihB, WhhF, WhhB,
                                     bihF, bihB, bhhF, bhhB,
                                     ring, flags, out);
  h_epi<<<256, 256, 0, stream>>>(out);
}

// Round 11
// 2330.431 us; speedup vs baseline: 2.6447x; 1.1920x over previous
//
#include <hip/hip_runtime.h>

// ---------------------------------------------------------------------------
// Bidirectional stacked GRU decoder. B=64, S=512, I=H=512, L=2. f32 I/O.
//
// Round-11 = R10 + 2-way batch split (batch chains are independent):
//   grid 256 WGs x 128 thr = l(2) x d(2) x beta(2) x colslice(32).
//   Each WG: 16 cols x 32 batches; weights (Wih+Whh 16-col slices, bf16)
//   LDS-resident; h master in registers. 8 independent pipelines
//   (l0,d,beta)->(l1,d,beta); all-to-all only among the 32 colslices of a
//   pipeline. Per-CU per-step ring bytes halved vs R10 (the dominant
//   latency term: agent-scope IC reads through one CU port).
// Sync: per-WG private 128B generation flags, 32-lane parallel poll,
// vmcnt(0) drain before flag, dout off-path. Ring depth 8.
// ---------------------------------------------------------------------------

#define B_ 64
#define S_ 512
#define H_ 512
#define G3_ 1536

typedef __attribute__((ext_vector_type(8))) __bf16 bf16x8;
typedef __attribute__((ext_vector_type(8))) short short8;
typedef __attribute__((ext_vector_type(2))) unsigned long long ull2;
typedef __attribute__((ext_vector_type(4))) float f32x4;
typedef unsigned long long ull;

__device__ __forceinline__ unsigned short f2b(float f) {
  union { float f; unsigned int i; } v; v.f = f;
  unsigned int x = v.i;
  return (unsigned short)((x + 0x7fffu + ((x >> 16) & 1u)) >> 16);
}
__device__ __forceinline__ bf16x8 load8(const unsigned short* p) {
  short8 s = *(const short8*)p;
  return __builtin_bit_cast(bf16x8, s);
}
__device__ __forceinline__ bf16x8 load8f(const float* p) {
  f32x4 a = *(const f32x4*)p, b = *(const f32x4*)(p + 4);
  short8 s;
  s[0] = (short)f2b(a[0]); s[1] = (short)f2b(a[1]);
  s[2] = (short)f2b(a[2]); s[3] = (short)f2b(a[3]);
  s[4] = (short)f2b(b[0]); s[5] = (short)f2b(b[1]);
  s[6] = (short)f2b(b[2]); s[7] = (short)f2b(b[3]);
  return __builtin_bit_cast(bf16x8, s);
}
__device__ __forceinline__ f32x4 mfma16(bf16x8 a, bf16x8 b, f32x4 c) {
  return __builtin_amdgcn_mfma_f32_16x16x32_bf16(a, b, c, 0, 0, 0);
}
__device__ __forceinline__ float sigmoidf_(float x) {
  float e = __expf(-fabsf(x));
  float s = e / (1.0f + e);
  return x >= 0.0f ? 1.0f - s : s;
}
__device__ __forceinline__ float tanhf_(float x) {
  float e = __expf(-2.0f * fabsf(x));
  float r = (1.0f - e) / (1.0f + e);
  return x >= 0.0f ? r : -r;
}
// agent-scope coherent 16B (2x8B) ring read -> bf16x8
__device__ __forceinline__ bf16x8 load16a(ull* p) {
  ull2 v;
  v[0] = __hip_atomic_load(p, __ATOMIC_RELAXED, __HIP_MEMORY_SCOPE_AGENT);
  v[1] = __hip_atomic_load(p + 1, __ATOMIC_RELAXED, __HIP_MEMORY_SCOPE_AGENT);
  return __builtin_bit_cast(bf16x8, v);
}
__device__ __forceinline__ bf16x8 load16p(const ull* p) {
  ull2 v = *(const ull2*)p;
  return __builtin_bit_cast(bf16x8, v);
}
__device__ __forceinline__ ull pack4(const float* f) {
  ull v = 0;
#pragma unroll
  for (int j = 0; j < 4; ++j) v |= (ull)f2b(f[j]) << (16 * j);
  return v;
}

// ---------------------------------------------------------------------------
// xc[t][cell(64)][b(64)][8 bf16]  <-  x[b][t][cell*8+j]
// ---------------------------------------------------------------------------
__global__ void cvt_x(const float* __restrict__ x, ull* __restrict__ xc) {
  int i = blockIdx.x * 256 + threadIdx.x;      // 0 .. 2^21-1
  int b = i & 63, cell = (i >> 6) & 63, txx = i >> 12;
  const float* src = x + ((size_t)b * 512 + txx) * 512 + cell * 8;
  float s0[4] = {src[0], src[1], src[2], src[3]};
  float s1[4] = {src[4], src[5], src[6], src[7]};
  size_t o = ((size_t)txx * 4096 + cell * 64 + b) * 2;
  xc[o]     = pack4(s0);
  xc[o + 1] = pack4(s1);
}

// ---------------------------------------------------------------------------
// init ring slot 7 ("h before step 0") per gid.
// ring[gid][slot(8)][cell(64)][b(32)][half(2)] ull;  gid = [l d beta]
// ---------------------------------------------------------------------------
__global__ void init_ring(const float* __restrict__ enc, ull* __restrict__ ring) {
  int i = blockIdx.x * 256 + threadIdx.x;      // 0..32767
  if (i >= 32768) return;
  int gid = i >> 12;                           // 0..7 (l=0 gids 0-3 used; fill all)
  int u = i & 4095;
  int d = (gid >> 1) & 1, beta = gid & 1;
  int half = u & 1, b = (u >> 1) & 31, cell = u >> 6;
  const float* e = enc + (size_t)(beta * 32 + b) * 1024 + d * 512 + cell * 8 + half * 4;
  float s[4] = {e[0], e[1], e[2], e[3]};
  ring[(size_t)gid * 32768 + 7 * 4096 + u] = pack4(s);
}

// ---------------------------------------------------------------------------
// Persistent fused GRU. Grid 256 = l(2) x d(2) x beta(2) x cb(32), block 128.
// flags: [gid(8)][wg(32)] x 32 ints (private 128B line per WG), value = t+1.
// ---------------------------------------------------------------------------
__global__ __launch_bounds__(128) void gru_fused(
    const float* __restrict__ x,               // [B][S][H] f32 (fallback path)
    const ull* __restrict__ xc, int usexc,     // coalesced bf16 x
    const float* __restrict__ enc,
    const float* __restrict__ WihF, const float* __restrict__ WihB,
    const float* __restrict__ WhhF, const float* __restrict__ WhhB,
    const float* __restrict__ bihF, const float* __restrict__ bihB,
    const float* __restrict__ bhhF, const float* __restrict__ bhhB,
    ull* __restrict__ ring,
    unsigned int* __restrict__ flags,
    float* __restrict__ dout) {                // [B][S][2H] f32
  __shared__ __align__(16) unsigned short wih2[24576];  // [gate][kk][lane][8]
  __shared__ __align__(16) unsigned short whh2[24576];
  __shared__ float hpub[32 * 20];              // [b_local][20] padded
  __shared__ int lcnt[8];

  const int tid = threadIdx.x;
  const int lane = tid & 63;
  const int wv = tid >> 6;                     // 0..1
  const int wg = (int)blockIdx.x;
  const int l = wg >> 7, d = (wg >> 6) & 1, beta = (wg >> 5) & 1, cb = wg & 31;
  const int gid = ((l * 2 + d) << 1) | beta;   // [l d beta]
  const int gidA = gid & 3;                    // l0 pipeline partner
  const int gidB = gidA | 4;                   // l1 pipeline partner
  const int colbase = cb * 16;
  const int rowA = lane & 15, kb = lane >> 4;

  const float* Wih = (d ? WihB : WihF) + (size_t)l * G3_ * H_;
  const float* Whh = (d ? WhhB : WhhF) + (size_t)l * G3_ * H_;
  const float* bi = (d ? bihB : bihF) + l * G3_;
  const float* bh = (d ? bhhB : bhhF) + l * G3_;

  if (tid < 8) lcnt[tid] = 0;
  // one-time LDS fill, layout [gate(3)][kk(16)][lane(64)][8]
  for (int i = tid; i < 3072; i += 128) {
    int gate = i >> 10;
    int rest = i & 1023;
    int kk = rest >> 6;
    int l6 = rest & 63;
    int c = l6 & 15, k = l6 >> 4;
    size_t gro = (size_t)(gate * 512 + colbase + c) * 512 + kk * 32 + k * 8;
    *(short8*)&wih2[i * 8] = __builtin_bit_cast(short8, load8f(Wih + gro));
    *(short8*)&whh2[i * 8] = __builtin_bit_cast(short8, load8f(Whh + gro));
  }
  __syncthreads();                             // prologue only

  const int col16 = rowA;
  const int hc = colbase + col16;
  const float brz_r = bi[hc] + bh[hc];
  const float brz_z = bi[512 + hc] + bh[512 + hc];
  const float bi_n = bi[1024 + hc];
  const float bh_n = bh[1024 + hc];

  const int bq = wv * 16 + kb * 4;             // local batch rows (0..31)
  const int arow = wv * 16 + rowA;             // local A row (0..31)

  float hm[4];
#pragma unroll
  for (int rg = 0; rg < 4; ++rg)
    hm[rg] = enc[(size_t)(beta * 32 + bq + rg) * 1024 + d * 512 + hc];

  unsigned int* flA = flags + gidA * 1024;     // 32 lines x 32 ints
  unsigned int* flB = flags + gidB * 1024;
  unsigned int* flo = flags + gid * 1024;
  ull* ringA = ring + (size_t)gidA * 32768;
  ull* ringl = ring + (size_t)gid * 32768;

  // publish mapping: one 8B word per thread
  const int pb = tid >> 2;                     // local batch 0..31
  const int pq = tid & 3;
  const int pcellL = pq >> 1, phalf = pq & 1;
  const int pc0 = pcellL * 8 + phalf * 4;
  const int pidx = ((2 * cb + pcellL) * 32 + pb) * 2 + phalf;

  for (int t = 0; t < 512; ++t) {
    // x A-frags (layer 0): flag-independent — issue before the poll
    bf16x8 aIn[16];
    if (l == 0) {
      int txx = d ? (511 - t) : t;
      if (usexc) {
        const ull* xp = xc + (size_t)txx * 8192;
#pragma unroll
        for (int kk = 0; kk < 16; ++kk)
          aIn[kk] = load16p(xp + (size_t)((kk * 4 + kb) * 64 + beta * 32 + arow) * 2);
      } else {
        const float* ap = x + ((size_t)(beta * 32 + arow) * 512 + txx) * 512 + kb * 8;
#pragma unroll
        for (int kk = 0; kk < 16; ++kk) aIn[kk] = load8f(ap + kk * 32);
      }
    }

    // generation poll (both waves poll; lanes watch private lines)
    // l0: flA(own) >= t, flB >= t-7 (slot reuse guard)
    // l1: flA(producer) >= t+1, flB(own) >= t
    {
      const int needA = (l == 0) ? t : (t + 1);
      const int needB = (l == 0) ? (t - 7) : t;
      unsigned int* watch;
      int need;
      if (lane < 32) { watch = flA + lane * 32;        need = needA; }
      else           { watch = flB + (lane - 32) * 32; need = needB; }
      if (need > 0) {
        while (__hip_atomic_load(watch, __ATOMIC_RELAXED,
                                 __HIP_MEMORY_SCOPE_AGENT) < (unsigned)need) {}
      }
    }
    asm volatile("" ::: "memory");             // no hoisting of ring reads

    if (l == 1) {                              // layer-0 output at step t
      ull* rp = ringA + (size_t)(t & 7) * 4096;
#pragma unroll
      for (int kk = 0; kk < 16; ++kk)
        aIn[kk] = load16a(rp + (size_t)((kk * 4 + kb) * 32 + arow) * 2);
    }
    ull* rpo = ringl + (size_t)((t + 7) & 7) * 4096;   // own h_{t-1}
    bf16x8 aOwn[16];
#pragma unroll
    for (int kk = 0; kk < 16; ++kk)
      aOwn[kk] = load16a(rpo + (size_t)((kk * 4 + kb) * 32 + arow) * 2);

    f32x4 accr = {0,0,0,0}, accz = {0,0,0,0}, acni = {0,0,0,0}, acnh = {0,0,0,0};
#pragma unroll
    for (int kk = 0; kk < 16; ++kk) {
      const int o = kk * 512 + lane * 8;       // [kk][lane][8] within gate blk
      accr = mfma16(aIn[kk],  load8(&wih2[o]), accr);
      accr = mfma16(aOwn[kk], load8(&whh2[o]), accr);
      accz = mfma16(aIn[kk],  load8(&wih2[8192 + o]), accz);
      accz = mfma16(aOwn[kk], load8(&whh2[8192 + o]), accz);
      acni = mfma16(aIn[kk],  load8(&wih2[16384 + o]), acni);
      acnh = mfma16(aOwn[kk], load8(&whh2[16384 + o]), acnh);
    }

#pragma unroll
    for (int rg = 0; rg < 4; ++rg) {
      float r = sigmoidf_(accr[rg] + brz_r);
      float z = sigmoidf_(accz[rg] + brz_z);
      float n = tanhf_(acni[rg] + bi_n + r * (acnh[rg] + bh_n));
      float hnew = (1.0f - z) * n + z * hm[rg];
      hm[rg] = hnew;
      hpub[(bq + rg) * 20 + col16] = hnew;     // wave-local staging
    }
    asm volatile("" ::: "memory");

    // publish own [32 b][16 col] slice to ring slot t&7 (1 word per thread)
    {
      f32x4 v4 = *(f32x4*)&hpub[pb * 20 + pc0];
      float s[4] = {v4[0], v4[1], v4[2], v4[3]};
      __hip_atomic_store(ringl + (size_t)(t & 7) * 4096 + pidx, pack4(s),
                         __ATOMIC_RELAXED, __HIP_MEMORY_SCOPE_AGENT);
    }
    asm volatile("s_waitcnt vmcnt(0)" ::: "memory");   // ring store at IC

    // intra-WG arrival (2 waves); second wave bumps this WG's generation flag
    if (lane == 0) {
      int old = atomicAdd(&lcnt[t & 7], 1);
      if (old == 1) {
        lcnt[t & 7] = 0;
        __hip_atomic_store(flo + cb * 32, (unsigned)(t + 1),
                           __ATOMIC_RELAXED, __HIP_MEMORY_SCOPE_AGENT);
      }
    }

    // dout stores AFTER the flag publish — off the critical chain
    if (l == 1) {
      const int tox = d ? (511 - t) : t;
#pragma unroll
      for (int rg = 0; rg < 4; ++rg)
        dout[((size_t)(beta * 32 + bq + rg) * 512 + tox) * 1024 + d * 512 + hc] = hm[rg];
    }
  }
}

// ---------------------------------------------------------------------------
// Final hidden epilogue: h_f = out[:, S-1, :H], h_b = out[:, 0, H:2H]
// ---------------------------------------------------------------------------
__global__ void h_epi(float* __restrict__ dout) {
  int i = blockIdx.x * 256 + threadIdx.x;      // 0 .. 65535
  if (i >= B_ * 2 * H_) return;
  int b = i >> 10, j = i & 1023;
  int t = (j < H_) ? (S_ - 1) : 0;
  dout[(size_t)B_ * S_ * 2 * H_ + i] = dout[((size_t)b * S_ + t) * (2 * H_) + j];
}

// ---------------------------------------------------------------------------
extern "C" void kernel_launch(void* const* d_in, const int* in_sizes, int n_in,
                              void* d_out, int out_size, void* d_ws, size_t ws_size,
                              hipStream_t stream) {
  const float* x    = (const float*)d_in[0];
  const float* enc  = (const float*)d_in[1];
  const float* WihF = (const float*)d_in[2];
  const float* WhhF = (const float*)d_in[3];
  const float* bihF = (const float*)d_in[4];
  const float* bhhF = (const float*)d_in[5];
  const float* WihB = (const float*)d_in[6];
  const float* WhhB = (const float*)d_in[7];
  const float* bihB = (const float*)d_in[8];
  const float* bhhB = (const float*)d_in[9];
  float* out = (float*)d_out;

  // ws: [flags 32KB (+pad to 64KB)][ring 2MB][xc 32MB (optional)]
  char* ws = (char*)d_ws;
  unsigned int* flags = (unsigned int*)ws;     // 8*32*128B = 32,768 B
  ull* ring  = (ull*)(ws + 65536);             // 8 gids * 32768 * 8B = 2,097,152 B
  ull* xc    = (ull*)(ws + 65536 + 2097152);   // 33,554,432 B
  const int usexc = (ws_size >= (size_t)65536 + 2097152 + 33554432) ? 1 : 0;

  (void)hipMemsetAsync(flags, 0, 32768, stream);
  if (usexc) cvt_x<<<8192, 256, 0, stream>>>(x, xc);
  init_ring<<<128, 256, 0, stream>>>(enc, ring);
  gru_fused<<<256, 128, 0, stream>>>(x, xc, usexc, enc,
                                     WihF, WihB, WhhF, WhhB,
                                     bihF, bihB, bhhF, bhhB,
                                     ring, flags, out);
  h_epi<<<256, 256, 0, stream>>>(out);
}